// Round 4
// baseline (5001.255 us; speedup 1.0000x reference)
//
#include <hip/hip_runtime.h>
#include <cstdint>
#include <cstddef>

#define BB 64
#define SS 2048
#define FF 128
#define HH 256
#define CC 10

typedef _Float16 f16;
typedef _Float16 f16x8 __attribute__((ext_vector_type(8)));
typedef _Float16 f16x4 __attribute__((ext_vector_type(4)));
typedef float f32x4 __attribute__((ext_vector_type(4)));

// ---------------------------------------------------------------------------
// GEMM: out[m,n] = sum_k X[m,k] * W[n,k] + b1[n] + b2[n]   (unchanged from R1)
// ---------------------------------------------------------------------------
template<int K>
__global__ __launch_bounds__(256)
void xproj_gemm(const float* __restrict__ X, const float* __restrict__ W,
                const float* __restrict__ b1, const float* __restrict__ b2,
                float* __restrict__ out)
{
    constexpr int BM = 64, BN = 64, BK = 32;
    __shared__ float As[BK][BM + 4];
    __shared__ float Ws[BK][BN + 4];

    const int m0 = blockIdx.x * BM;
    const int n0 = blockIdx.y * BN;
    const int tid = (int)threadIdx.x;
    const int tm = tid & 15;
    const int tn = tid >> 4;
    const int lr = tid >> 3;
    const int lc = tid & 7;

    float acc[4][4];
    #pragma unroll
    for (int i = 0; i < 4; ++i)
        #pragma unroll
        for (int jj = 0; jj < 4; ++jj) acc[i][jj] = 0.f;

    for (int k0 = 0; k0 < K; k0 += BK) {
        float4 a0 = *(const float4*)&X[(size_t)(m0 + lr) * K + k0 + lc * 4];
        float4 a1 = *(const float4*)&X[(size_t)(m0 + lr + 32) * K + k0 + lc * 4];
        float4 w0 = *(const float4*)&W[(size_t)(n0 + lr) * K + k0 + lc * 4];
        float4 w1 = *(const float4*)&W[(size_t)(n0 + lr + 32) * K + k0 + lc * 4];
        As[lc*4+0][lr]    = a0.x; As[lc*4+1][lr]    = a0.y; As[lc*4+2][lr]    = a0.z; As[lc*4+3][lr]    = a0.w;
        As[lc*4+0][lr+32] = a1.x; As[lc*4+1][lr+32] = a1.y; As[lc*4+2][lr+32] = a1.z; As[lc*4+3][lr+32] = a1.w;
        Ws[lc*4+0][lr]    = w0.x; Ws[lc*4+1][lr]    = w0.y; Ws[lc*4+2][lr]    = w0.z; Ws[lc*4+3][lr]    = w0.w;
        Ws[lc*4+0][lr+32] = w1.x; Ws[lc*4+1][lr+32] = w1.y; Ws[lc*4+2][lr+32] = w1.z; Ws[lc*4+3][lr+32] = w1.w;
        __syncthreads();
        #pragma unroll
        for (int k = 0; k < BK; ++k) {
            float4 av = *(const float4*)&As[k][tm * 4];
            float4 wv = *(const float4*)&Ws[k][tn * 4];
            acc[0][0] = fmaf(av.x, wv.x, acc[0][0]);
            acc[0][1] = fmaf(av.x, wv.y, acc[0][1]);
            acc[0][2] = fmaf(av.x, wv.z, acc[0][2]);
            acc[0][3] = fmaf(av.x, wv.w, acc[0][3]);
            acc[1][0] = fmaf(av.y, wv.x, acc[1][0]);
            acc[1][1] = fmaf(av.y, wv.y, acc[1][1]);
            acc[1][2] = fmaf(av.y, wv.z, acc[1][2]);
            acc[1][3] = fmaf(av.y, wv.w, acc[1][3]);
            acc[2][0] = fmaf(av.z, wv.x, acc[2][0]);
            acc[2][1] = fmaf(av.z, wv.y, acc[2][1]);
            acc[2][2] = fmaf(av.z, wv.z, acc[2][2]);
            acc[2][3] = fmaf(av.z, wv.w, acc[2][3]);
            acc[3][0] = fmaf(av.w, wv.x, acc[3][0]);
            acc[3][1] = fmaf(av.w, wv.y, acc[3][1]);
            acc[3][2] = fmaf(av.w, wv.z, acc[3][2]);
            acc[3][3] = fmaf(av.w, wv.w, acc[3][3]);
        }
        __syncthreads();
    }

    float4 bv1 = *(const float4*)&b1[n0 + tn * 4];
    float4 bv2 = *(const float4*)&b2[n0 + tn * 4];
    float bs0 = bv1.x + bv2.x, bs1 = bv1.y + bv2.y, bs2 = bv1.z + bv2.z, bs3 = bv1.w + bv2.w;
    #pragma unroll
    for (int i = 0; i < 4; ++i) {
        float4 o;
        o.x = acc[i][0] + bs0;
        o.y = acc[i][1] + bs1;
        o.z = acc[i][2] + bs2;
        o.w = acc[i][3] + bs3;
        *(float4*)&out[(size_t)(m0 + tm * 4 + i) * HH + n0 + tn * 4] = o;
    }
}

// ---------------------------------------------------------------------------
// MFMA Elman scan. Grid = 4 blocks (16 batch rows each), 256 threads (4 waves).
// Orientation: D[M=j, N=batch].  A = Whh (f16 frags, registers, wave w owns
// j in [64w, 64w+64)).  B = h (f16, LDS, XOR-swizzled, double-buffered).
// xp is read directly from global in D-fragment order (full-line coalesced)
// and used as the MFMA C operand (no separate add).
//
// Fragment layouts (16x16x32, verified per learn_hip m89/m92):
//   A: lane l holds row (l&15), k = (l>>4)*8 + e  (8 contiguous f16)
//   B: lane l holds col (l&15), k = (l>>4)*8 + e
//   C/D: lane l holds col (l&15), row = (l>>4)*4 + reg
// ---------------------------------------------------------------------------
__global__ __launch_bounds__(256, 1)
void rnn_scan_mfma(const float* __restrict__ xproj,   // [B,S,H] fp32 (x-proj + biases)
                   const float* __restrict__ Whh,     // [H,H] fp32
                   float* __restrict__ hout,          // [B,S,H] fp32 or nullptr
                   const float* __restrict__ Wd,      // [C,H] or nullptr
                   const float* __restrict__ bd,      // [C] or nullptr
                   float* __restrict__ outfinal,      // [B,C] or nullptr
                   int storeH)
{
    __shared__ __align__(16) f16 hbuf[2][16][HH];   // 16 KiB, XOR-swizzled cols
    const int bg  = blockIdx.x;          // batch group: batches [16bg, 16bg+16)
    const int tid = (int)threadIdx.x;
    const int w   = tid >> 6;            // wave 0..3
    const int l   = tid & 63;
    const int l15 = l & 15;              // batch-within-group (B/C/D col)
    const int lq  = l >> 4;              // 0..3
    const int swz = (l15 & 7) << 4;      // per-row XOR swizzle (flips byte bits 4..6)

    // ---- Whh -> f16 A-fragments (one-time; amortized over 2048 steps) ----
    f16x8 a[4][8];
    #pragma unroll
    for (int mt = 0; mt < 4; ++mt) {
        const int jrow = 64 * w + 16 * mt + l15;
        #pragma unroll
        for (int kt = 0; kt < 8; ++kt) {
            const float* src = Whh + (size_t)jrow * HH + 32 * kt + 8 * lq;
            float4 lo = *(const float4*)src;
            float4 hi = *(const float4*)(src + 4);
            f16x8 v;
            v[0] = (f16)lo.x; v[1] = (f16)lo.y; v[2] = (f16)lo.z; v[3] = (f16)lo.w;
            v[4] = (f16)hi.x; v[5] = (f16)hi.y; v[6] = (f16)hi.z; v[7] = (f16)hi.w;
            a[mt][kt] = v;
        }
    }

    // zero h buffer 0 (8 KiB)
    for (int i = tid; i < 2048; i += 256) ((uint32_t*)hbuf)[i] = 0u;
    __syncthreads();

    const float* xpb = xproj + (size_t)(bg * 16) * SS * HH;
    const int j0base = 64 * w + 4 * lq;              // j0 for mt: + 16*mt
    float* hob = storeH ? (hout + (size_t)(bg * 16) * SS * HH) : nullptr;

    // prologue: xp(t=0) into regs (D-fragment order: lane l -> batch=l15, j=j0+r)
    float4 xpv[4];
    #pragma unroll
    for (int mt = 0; mt < 4; ++mt)
        xpv[mt] = *(const float4*)(xpb + (size_t)l15 * SS * HH + j0base + 16 * mt);

    int cur = 0;
    for (int t = 0; t < SS; ++t) {
        // B fragments from hbuf[cur] (row = batch = l15)
        f16x8 bfr[8];
        const char* hrow = (const char*)&hbuf[cur][l15][0];
        #pragma unroll
        for (int kt = 0; kt < 8; ++kt) {
            const int kb = (64 * kt + 16 * lq) ^ swz;   // 16B-aligned
            bfr[kt] = *(const f16x8*)(hrow + kb);
        }

        // prefetch xp(t+1) (consumed next iteration; overlaps MFMA + epilogue)
        const int tn = (t + 1 < SS) ? (t + 1) : t;
        float4 xpn[4];
        #pragma unroll
        for (int mt = 0; mt < 4; ++mt)
            xpn[mt] = *(const float4*)(xpb + ((size_t)l15 * SS + tn) * HH + j0base + 16 * mt);

        // MFMA with C initialized to xp (saves the adds)
        f32x4 acc[4];
        #pragma unroll
        for (int mt = 0; mt < 4; ++mt) {
            acc[mt][0] = xpv[mt].x; acc[mt][1] = xpv[mt].y;
            acc[mt][2] = xpv[mt].z; acc[mt][3] = xpv[mt].w;
        }
        #pragma unroll
        for (int kt = 0; kt < 8; ++kt)
            #pragma unroll
            for (int mt = 0; mt < 4; ++mt)
                acc[mt] = __builtin_amdgcn_mfma_f32_16x16x32_f16(a[mt][kt], bfr[kt], acc[mt], 0, 0, 0);

        // epilogue: tanh, f16 pack -> hbuf[cur^1]; optional fp32 h-seq store
        #pragma unroll
        for (int mt = 0; mt < 4; ++mt) {
            float4 hv;
            f16x4 h4;
            float* hvp = &hv.x;
            #pragma unroll
            for (int r = 0; r < 4; ++r) {
                float z = acc[mt][r];
                // tanh(z) = 1 - 2/(exp(2z)+1); saturates correctly at +/-1
                float e = __expf(2.0f * z);
                float ht = 1.0f - 2.0f * __builtin_amdgcn_rcpf(e + 1.0f);
                hvp[r] = ht;
                h4[r] = (f16)ht;
            }
            const int jb = (128 * w + 32 * mt + 8 * lq) ^ swz;   // byte col = 2*j0, 8B-aligned
            *(f16x4*)((char*)&hbuf[cur ^ 1][l15][0] + jb) = h4;
            if (hob)
                *(float4*)(hob + ((size_t)l15 * SS + t) * HH + j0base + 16 * mt) = hv;
        }
        __syncthreads();   // one barrier/step: reads of [cur] precede it, writes of
                           // [cur^1] precede it, next iter reads [cur^1] after it
        cur ^= 1;
        #pragma unroll
        for (int mt = 0; mt < 4; ++mt) xpv[mt] = xpn[mt];
    }

    // final linear head (last layer): out[b,c] = dot(h_last, Wd[c,:]) + bd[c]
    if (outfinal != nullptr && tid < 16 * CC) {
        const int b = tid / CC, c = tid - CC * b;
        const int sw = (b & 7) << 4;
        const char* hrow = (const char*)&hbuf[cur][b][0];
        float accv = bd[c];
        for (int k = 0; k < HH; ++k) {
            f16 hv = *(const f16*)(hrow + ((2 * k) ^ sw));
            accv += (float)hv * Wd[(size_t)c * HH + k];
        }
        outfinal[(size_t)(bg * 16 + b) * CC + c] = accv;
    }
}

// ---------------------------------------------------------------------------
extern "C" void kernel_launch(void* const* d_in, const int* in_sizes, int n_in,
                              void* d_out, int out_size, void* d_ws, size_t ws_size,
                              hipStream_t stream)
{
    const float* x    = (const float*)d_in[0];
    const float* Wih0 = (const float*)d_in[1];
    const float* Whh0 = (const float*)d_in[2];
    const float* bih0 = (const float*)d_in[3];
    const float* bhh0 = (const float*)d_in[4];
    const float* Wih1 = (const float*)d_in[5];
    const float* Whh1 = (const float*)d_in[6];
    const float* bih1 = (const float*)d_in[7];
    const float* bhh1 = (const float*)d_in[8];
    const float* Wd   = (const float*)d_in[9];
    const float* bd   = (const float*)d_in[10];
    float* out = (float*)d_out;

    float* xp = (float*)d_ws;                          // [B*S*H] fp32 = 134 MB
    float* h1 = xp + (size_t)BB * SS * HH;             // [B*S*H] fp32 = 134 MB

    dim3 gemm_grid(BB * SS / 64, HH / 64);             // (2048, 4)

    // Layer 0
    xproj_gemm<FF><<<gemm_grid, 256, 0, stream>>>(x, Wih0, bih0, bhh0, xp);
    rnn_scan_mfma<<<4, 256, 0, stream>>>(xp, Whh0, h1, nullptr, nullptr, nullptr, 1);

    // Layer 1 + head
    xproj_gemm<HH><<<gemm_grid, 256, 0, stream>>>(h1, Wih1, bih1, bhh1, xp);
    rnn_scan_mfma<<<4, 256, 0, stream>>>(xp, Whh1, nullptr, Wd, bd, out, 0);
}

// Round 5
// 4744.854 us; speedup vs baseline: 1.0540x; 1.0540x over previous
//
#include <hip/hip_runtime.h>
#include <cstdint>
#include <cstddef>

#define BB 64
#define SS 2048
#define FF 128
#define HH 256
#define CC 10

typedef _Float16 f16;
typedef _Float16 f16x8 __attribute__((ext_vector_type(8)));
typedef _Float16 f16x4 __attribute__((ext_vector_type(4)));
typedef float f32x4 __attribute__((ext_vector_type(4)));

// ---------------------------------------------------------------------------
// GEMM (f32 X): out[m,n] = sum_k X[m,k]*W[n,k] + b1[n] + b2[n]
// ---------------------------------------------------------------------------
template<int K>
__global__ __launch_bounds__(256)
void xproj_gemm(const float* __restrict__ X, const float* __restrict__ W,
                const float* __restrict__ b1, const float* __restrict__ b2,
                float* __restrict__ out)
{
    constexpr int BM = 64, BN = 64, BK = 32;
    __shared__ float As[BK][BM + 4];
    __shared__ float Ws[BK][BN + 4];

    const int m0 = blockIdx.x * BM;
    const int n0 = blockIdx.y * BN;
    const int tid = (int)threadIdx.x;
    const int tm = tid & 15;
    const int tn = tid >> 4;
    const int lr = tid >> 3;
    const int lc = tid & 7;

    float acc[4][4];
    #pragma unroll
    for (int i = 0; i < 4; ++i)
        #pragma unroll
        for (int jj = 0; jj < 4; ++jj) acc[i][jj] = 0.f;

    for (int k0 = 0; k0 < K; k0 += BK) {
        float4 a0 = *(const float4*)&X[(size_t)(m0 + lr) * K + k0 + lc * 4];
        float4 a1 = *(const float4*)&X[(size_t)(m0 + lr + 32) * K + k0 + lc * 4];
        float4 w0 = *(const float4*)&W[(size_t)(n0 + lr) * K + k0 + lc * 4];
        float4 w1 = *(const float4*)&W[(size_t)(n0 + lr + 32) * K + k0 + lc * 4];
        As[lc*4+0][lr]    = a0.x; As[lc*4+1][lr]    = a0.y; As[lc*4+2][lr]    = a0.z; As[lc*4+3][lr]    = a0.w;
        As[lc*4+0][lr+32] = a1.x; As[lc*4+1][lr+32] = a1.y; As[lc*4+2][lr+32] = a1.z; As[lc*4+3][lr+32] = a1.w;
        Ws[lc*4+0][lr]    = w0.x; Ws[lc*4+1][lr]    = w0.y; Ws[lc*4+2][lr]    = w0.z; Ws[lc*4+3][lr]    = w0.w;
        Ws[lc*4+0][lr+32] = w1.x; Ws[lc*4+1][lr+32] = w1.y; Ws[lc*4+2][lr+32] = w1.z; Ws[lc*4+3][lr+32] = w1.w;
        __syncthreads();
        #pragma unroll
        for (int k = 0; k < BK; ++k) {
            float4 av = *(const float4*)&As[k][tm * 4];
            float4 wv = *(const float4*)&Ws[k][tn * 4];
            acc[0][0] = fmaf(av.x, wv.x, acc[0][0]);
            acc[0][1] = fmaf(av.x, wv.y, acc[0][1]);
            acc[0][2] = fmaf(av.x, wv.z, acc[0][2]);
            acc[0][3] = fmaf(av.x, wv.w, acc[0][3]);
            acc[1][0] = fmaf(av.y, wv.x, acc[1][0]);
            acc[1][1] = fmaf(av.y, wv.y, acc[1][1]);
            acc[1][2] = fmaf(av.y, wv.z, acc[1][2]);
            acc[1][3] = fmaf(av.y, wv.w, acc[1][3]);
            acc[2][0] = fmaf(av.z, wv.x, acc[2][0]);
            acc[2][1] = fmaf(av.z, wv.y, acc[2][1]);
            acc[2][2] = fmaf(av.z, wv.z, acc[2][2]);
            acc[2][3] = fmaf(av.z, wv.w, acc[2][3]);
            acc[3][0] = fmaf(av.w, wv.x, acc[3][0]);
            acc[3][1] = fmaf(av.w, wv.y, acc[3][1]);
            acc[3][2] = fmaf(av.w, wv.z, acc[3][2]);
            acc[3][3] = fmaf(av.w, wv.w, acc[3][3]);
        }
        __syncthreads();
    }

    float4 bv1 = *(const float4*)&b1[n0 + tn * 4];
    float4 bv2 = *(const float4*)&b2[n0 + tn * 4];
    float bs0 = bv1.x + bv2.x, bs1 = bv1.y + bv2.y, bs2 = bv1.z + bv2.z, bs3 = bv1.w + bv2.w;
    #pragma unroll
    for (int i = 0; i < 4; ++i) {
        float4 o;
        o.x = acc[i][0] + bs0;
        o.y = acc[i][1] + bs1;
        o.z = acc[i][2] + bs2;
        o.w = acc[i][3] + bs3;
        *(float4*)&out[(size_t)(m0 + tm * 4 + i) * HH + n0 + tn * 4] = o;
    }
}

// ---------------------------------------------------------------------------
// GEMM variant with f16 X input (layer-1 xproj over the f16 h1 sequence).
// Same tiling; A loader converts f16->f32 into LDS.
// ---------------------------------------------------------------------------
__global__ __launch_bounds__(256)
void xproj_gemm_f16(const f16* __restrict__ X, const float* __restrict__ W,
                    const float* __restrict__ b1, const float* __restrict__ b2,
                    float* __restrict__ out)
{
    constexpr int K = HH, BM = 64, BN = 64, BK = 32;
    __shared__ float As[BK][BM + 4];
    __shared__ float Ws[BK][BN + 4];

    const int m0 = blockIdx.x * BM;
    const int n0 = blockIdx.y * BN;
    const int tid = (int)threadIdx.x;
    const int tm = tid & 15;
    const int tn = tid >> 4;
    const int ar = tid >> 2;        // 0..63  A-loader row
    const int ac = tid & 3;         // 0..3   A-loader col-group (x8 f16)
    const int lr = tid >> 3;        // 0..31  W-loader row
    const int lc = tid & 7;         // 0..7   W-loader k-group (x4)

    float acc[4][4];
    #pragma unroll
    for (int i = 0; i < 4; ++i)
        #pragma unroll
        for (int jj = 0; jj < 4; ++jj) acc[i][jj] = 0.f;

    for (int k0 = 0; k0 < K; k0 += BK) {
        f16x8 a8 = *(const f16x8*)&X[(size_t)(m0 + ar) * K + k0 + ac * 8];
        float4 w0 = *(const float4*)&W[(size_t)(n0 + lr) * K + k0 + lc * 4];
        float4 w1 = *(const float4*)&W[(size_t)(n0 + lr + 32) * K + k0 + lc * 4];
        #pragma unroll
        for (int e = 0; e < 8; ++e) As[ac * 8 + e][ar] = (float)a8[e];
        Ws[lc*4+0][lr]    = w0.x; Ws[lc*4+1][lr]    = w0.y; Ws[lc*4+2][lr]    = w0.z; Ws[lc*4+3][lr]    = w0.w;
        Ws[lc*4+0][lr+32] = w1.x; Ws[lc*4+1][lr+32] = w1.y; Ws[lc*4+2][lr+32] = w1.z; Ws[lc*4+3][lr+32] = w1.w;
        __syncthreads();
        #pragma unroll
        for (int k = 0; k < BK; ++k) {
            float4 av = *(const float4*)&As[k][tm * 4];
            float4 wv = *(const float4*)&Ws[k][tn * 4];
            acc[0][0] = fmaf(av.x, wv.x, acc[0][0]);
            acc[0][1] = fmaf(av.x, wv.y, acc[0][1]);
            acc[0][2] = fmaf(av.x, wv.z, acc[0][2]);
            acc[0][3] = fmaf(av.x, wv.w, acc[0][3]);
            acc[1][0] = fmaf(av.y, wv.x, acc[1][0]);
            acc[1][1] = fmaf(av.y, wv.y, acc[1][1]);
            acc[1][2] = fmaf(av.y, wv.z, acc[1][2]);
            acc[1][3] = fmaf(av.y, wv.w, acc[1][3]);
            acc[2][0] = fmaf(av.z, wv.x, acc[2][0]);
            acc[2][1] = fmaf(av.z, wv.y, acc[2][1]);
            acc[2][2] = fmaf(av.z, wv.z, acc[2][2]);
            acc[2][3] = fmaf(av.z, wv.w, acc[2][3]);
            acc[3][0] = fmaf(av.w, wv.x, acc[3][0]);
            acc[3][1] = fmaf(av.w, wv.y, acc[3][1]);
            acc[3][2] = fmaf(av.w, wv.z, acc[3][2]);
            acc[3][3] = fmaf(av.w, wv.w, acc[3][3]);
        }
        __syncthreads();
    }

    float4 bv1 = *(const float4*)&b1[n0 + tn * 4];
    float4 bv2 = *(const float4*)&b2[n0 + tn * 4];
    float bs0 = bv1.x + bv2.x, bs1 = bv1.y + bv2.y, bs2 = bv1.z + bv2.z, bs3 = bv1.w + bv2.w;
    #pragma unroll
    for (int i = 0; i < 4; ++i) {
        float4 o;
        o.x = acc[i][0] + bs0;
        o.y = acc[i][1] + bs1;
        o.z = acc[i][2] + bs2;
        o.w = acc[i][3] + bs3;
        *(float4*)&out[(size_t)(m0 + tm * 4 + i) * HH + n0 + tn * 4] = o;
    }
}

// ---------------------------------------------------------------------------
// MFMA Elman scan, 8 waves (512 threads), 4 blocks (16 batches each).
// Wave w owns j in [32w, 32w+32) -> 2 mt tiles, 16 MFMA + 8 tanh/lane/step.
// 2 waves/SIMD: one wave's MFMA/VALU hides the other's LDS/global latency
// (R2's 4-wave version had 1 wave/SIMD -> fully exposed latency, 2707us).
// h: f16 in LDS, XOR-swizzled, double-buffered; xp folded into MFMA C.
// ---------------------------------------------------------------------------
__global__ __launch_bounds__(512, 2)
void rnn_scan_mfma(const float* __restrict__ xproj,   // [B,S,H] fp32 (x-proj + biases)
                   const float* __restrict__ Whh,     // [H,H] fp32
                   f16* __restrict__ hout,            // [B,S,H] f16 or nullptr
                   const float* __restrict__ Wd,      // [C,H] or nullptr
                   const float* __restrict__ bd,      // [C] or nullptr
                   float* __restrict__ outfinal,      // [B,C] or nullptr
                   int storeH)
{
    __shared__ __align__(16) f16 hbuf[2][16][HH];   // 16 KiB
    const int bg  = blockIdx.x;
    const int tid = (int)threadIdx.x;
    const int w   = tid >> 6;            // wave 0..7
    const int l   = tid & 63;
    const int l15 = l & 15;              // batch-within-group
    const int lq  = l >> 4;              // 0..3
    const int swz = (l15 & 7) << 4;

    // Whh -> f16 A-fragments: wave w rows [32w, 32w+32), mt in {0,1}
    f16x8 a[2][8];
    #pragma unroll
    for (int mt = 0; mt < 2; ++mt) {
        const int jrow = 32 * w + 16 * mt + l15;
        #pragma unroll
        for (int kt = 0; kt < 8; ++kt) {
            const float* src = Whh + (size_t)jrow * HH + 32 * kt + 8 * lq;
            float4 lo = *(const float4*)src;
            float4 hi = *(const float4*)(src + 4);
            f16x8 v;
            v[0] = (f16)lo.x; v[1] = (f16)lo.y; v[2] = (f16)lo.z; v[3] = (f16)lo.w;
            v[4] = (f16)hi.x; v[5] = (f16)hi.y; v[6] = (f16)hi.z; v[7] = (f16)hi.w;
            a[mt][kt] = v;
        }
    }

    for (int i = tid; i < 2048; i += 512) ((uint32_t*)hbuf)[i] = 0u;  // zero hbuf[0]
    __syncthreads();

    const float* xpb = xproj + (size_t)(bg * 16) * SS * HH;
    const int j0base = 32 * w + 4 * lq;              // + 16*mt per tile
    f16* hob = storeH ? (hout + (size_t)(bg * 16) * SS * HH) : nullptr;

    float4 xpv[2];
    #pragma unroll
    for (int mt = 0; mt < 2; ++mt)
        xpv[mt] = *(const float4*)(xpb + (size_t)l15 * SS * HH + j0base + 16 * mt);

    int cur = 0;
    for (int t = 0; t < SS; ++t) {
        // B fragments: full K=256 h-tile (shared operand; every wave reads it)
        f16x8 bfr[8];
        const char* hrow = (const char*)&hbuf[cur][l15][0];
        #pragma unroll
        for (int kt = 0; kt < 8; ++kt) {
            const int kb = (64 * kt + 16 * lq) ^ swz;
            bfr[kt] = *(const f16x8*)(hrow + kb);
        }

        // prefetch xp(t+1): consumed next iter, hidden under MFMA+epilogue
        const int tn = (t + 1 < SS) ? (t + 1) : t;
        float4 xpn[2];
        #pragma unroll
        for (int mt = 0; mt < 2; ++mt)
            xpn[mt] = *(const float4*)(xpb + ((size_t)l15 * SS + tn) * HH + j0base + 16 * mt);

        f32x4 acc[2];
        #pragma unroll
        for (int mt = 0; mt < 2; ++mt) {
            acc[mt][0] = xpv[mt].x; acc[mt][1] = xpv[mt].y;
            acc[mt][2] = xpv[mt].z; acc[mt][3] = xpv[mt].w;
        }
        #pragma unroll
        for (int kt = 0; kt < 8; ++kt)
            #pragma unroll
            for (int mt = 0; mt < 2; ++mt)
                acc[mt] = __builtin_amdgcn_mfma_f32_16x16x32_f16(a[mt][kt], bfr[kt], acc[mt], 0, 0, 0);

        #pragma unroll
        for (int mt = 0; mt < 2; ++mt) {
            f16x4 h4;
            #pragma unroll
            for (int r = 0; r < 4; ++r) {
                float z = acc[mt][r];
                float e = __expf(2.0f * z);                       // v_mul + v_exp
                float ht = 1.0f - 2.0f * __builtin_amdgcn_rcpf(e + 1.0f);
                h4[r] = (f16)ht;
            }
            const int jb = (64 * w + 32 * mt + 8 * lq) ^ swz;     // byte col = 2*j0
            *(f16x4*)((char*)&hbuf[cur ^ 1][l15][0] + jb) = h4;
            if (hob)
                *(f16x4*)(hob + ((size_t)l15 * SS + t) * HH + j0base + 16 * mt) = h4;
        }
        __syncthreads();
        cur ^= 1;
        #pragma unroll
        for (int mt = 0; mt < 2; ++mt) xpv[mt] = xpn[mt];
    }

    // final head: out[b,c] = dot(h_last, Wd[c,:]) + bd[c]
    if (outfinal != nullptr && tid < 16 * CC) {
        const int b = tid / CC, c = tid - CC * b;
        const int sw = (b & 7) << 4;
        const char* hrow = (const char*)&hbuf[cur][b][0];
        float accv = bd[c];
        for (int k = 0; k < HH; ++k) {
            f16 hv = *(const f16*)(hrow + ((2 * k) ^ sw));
            accv += (float)hv * Wd[(size_t)c * HH + k];
        }
        outfinal[(size_t)(bg * 16 + b) * CC + c] = accv;
    }
}

// ---------------------------------------------------------------------------
extern "C" void kernel_launch(void* const* d_in, const int* in_sizes, int n_in,
                              void* d_out, int out_size, void* d_ws, size_t ws_size,
                              hipStream_t stream)
{
    const float* x    = (const float*)d_in[0];
    const float* Wih0 = (const float*)d_in[1];
    const float* Whh0 = (const float*)d_in[2];
    const float* bih0 = (const float*)d_in[3];
    const float* bhh0 = (const float*)d_in[4];
    const float* Wih1 = (const float*)d_in[5];
    const float* Whh1 = (const float*)d_in[6];
    const float* bih1 = (const float*)d_in[7];
    const float* bhh1 = (const float*)d_in[8];
    const float* Wd   = (const float*)d_in[9];
    const float* bd   = (const float*)d_in[10];
    float* out = (float*)d_out;

    float* xp = (float*)d_ws;                          // [B*S*H] fp32 = 134 MB
    f16*   h1 = (f16*)(xp + (size_t)BB * SS * HH);     // [B*S*H] f16 = 67 MB

    dim3 gemm_grid(BB * SS / 64, HH / 64);             // (2048, 4)

    // Layer 0
    xproj_gemm<FF><<<gemm_grid, 256, 0, stream>>>(x, Wih0, bih0, bhh0, xp);
    rnn_scan_mfma<<<4, 512, 0, stream>>>(xp, Whh0, h1, nullptr, nullptr, nullptr, 1);

    // Layer 1 + head
    xproj_gemm_f16<<<gemm_grid, 256, 0, stream>>>(h1, Wih1, bih1, bhh1, xp);
    rnn_scan_mfma<<<4, 512, 0, stream>>>(xp, Whh1, nullptr, Wd, bd, out, 0);
}

// Round 6
// 4032.757 us; speedup vs baseline: 1.2402x; 1.1766x over previous
//
#include <hip/hip_runtime.h>
#include <cstdint>
#include <cstddef>

#define BB 64
#define SS 2048
#define FF 128
#define HH 256
#define CC 10

typedef _Float16 f16;
typedef _Float16 f16x8 __attribute__((ext_vector_type(8)));
typedef _Float16 f16x4 __attribute__((ext_vector_type(4)));
typedef float f32x4 __attribute__((ext_vector_type(4)));

// ---------------------------------------------------------------------------
// GEMM (f32 X): xp[m,n] = sum_k X[m,k]*W[n,k] + b1[n] + b2[n], stored f16.
// ---------------------------------------------------------------------------
template<int K>
__global__ __launch_bounds__(256)
void xproj_gemm(const float* __restrict__ X, const float* __restrict__ W,
                const float* __restrict__ b1, const float* __restrict__ b2,
                f16* __restrict__ out)
{
    constexpr int BM = 64, BN = 64, BK = 32;
    __shared__ float As[BK][BM + 4];
    __shared__ float Ws[BK][BN + 4];

    const int m0 = blockIdx.x * BM;
    const int n0 = blockIdx.y * BN;
    const int tid = (int)threadIdx.x;
    const int tm = tid & 15;
    const int tn = tid >> 4;
    const int lr = tid >> 3;
    const int lc = tid & 7;

    float acc[4][4];
    #pragma unroll
    for (int i = 0; i < 4; ++i)
        #pragma unroll
        for (int jj = 0; jj < 4; ++jj) acc[i][jj] = 0.f;

    for (int k0 = 0; k0 < K; k0 += BK) {
        float4 a0 = *(const float4*)&X[(size_t)(m0 + lr) * K + k0 + lc * 4];
        float4 a1 = *(const float4*)&X[(size_t)(m0 + lr + 32) * K + k0 + lc * 4];
        float4 w0 = *(const float4*)&W[(size_t)(n0 + lr) * K + k0 + lc * 4];
        float4 w1 = *(const float4*)&W[(size_t)(n0 + lr + 32) * K + k0 + lc * 4];
        As[lc*4+0][lr]    = a0.x; As[lc*4+1][lr]    = a0.y; As[lc*4+2][lr]    = a0.z; As[lc*4+3][lr]    = a0.w;
        As[lc*4+0][lr+32] = a1.x; As[lc*4+1][lr+32] = a1.y; As[lc*4+2][lr+32] = a1.z; As[lc*4+3][lr+32] = a1.w;
        Ws[lc*4+0][lr]    = w0.x; Ws[lc*4+1][lr]    = w0.y; Ws[lc*4+2][lr]    = w0.z; Ws[lc*4+3][lr]    = w0.w;
        Ws[lc*4+0][lr+32] = w1.x; Ws[lc*4+1][lr+32] = w1.y; Ws[lc*4+2][lr+32] = w1.z; Ws[lc*4+3][lr+32] = w1.w;
        __syncthreads();
        #pragma unroll
        for (int k = 0; k < BK; ++k) {
            float4 av = *(const float4*)&As[k][tm * 4];
            float4 wv = *(const float4*)&Ws[k][tn * 4];
            acc[0][0] = fmaf(av.x, wv.x, acc[0][0]);
            acc[0][1] = fmaf(av.x, wv.y, acc[0][1]);
            acc[0][2] = fmaf(av.x, wv.z, acc[0][2]);
            acc[0][3] = fmaf(av.x, wv.w, acc[0][3]);
            acc[1][0] = fmaf(av.y, wv.x, acc[1][0]);
            acc[1][1] = fmaf(av.y, wv.y, acc[1][1]);
            acc[1][2] = fmaf(av.y, wv.z, acc[1][2]);
            acc[1][3] = fmaf(av.y, wv.w, acc[1][3]);
            acc[2][0] = fmaf(av.z, wv.x, acc[2][0]);
            acc[2][1] = fmaf(av.z, wv.y, acc[2][1]);
            acc[2][2] = fmaf(av.z, wv.z, acc[2][2]);
            acc[2][3] = fmaf(av.z, wv.w, acc[2][3]);
            acc[3][0] = fmaf(av.w, wv.x, acc[3][0]);
            acc[3][1] = fmaf(av.w, wv.y, acc[3][1]);
            acc[3][2] = fmaf(av.w, wv.z, acc[3][2]);
            acc[3][3] = fmaf(av.w, wv.w, acc[3][3]);
        }
        __syncthreads();
    }

    float4 bv1 = *(const float4*)&b1[n0 + tn * 4];
    float4 bv2 = *(const float4*)&b2[n0 + tn * 4];
    float bs0 = bv1.x + bv2.x, bs1 = bv1.y + bv2.y, bs2 = bv1.z + bv2.z, bs3 = bv1.w + bv2.w;
    #pragma unroll
    for (int i = 0; i < 4; ++i) {
        f16x4 o;
        o[0] = (f16)(acc[i][0] + bs0);
        o[1] = (f16)(acc[i][1] + bs1);
        o[2] = (f16)(acc[i][2] + bs2);
        o[3] = (f16)(acc[i][3] + bs3);
        *(f16x4*)&out[(size_t)(m0 + tm * 4 + i) * HH + n0 + tn * 4] = o;
    }
}

// ---------------------------------------------------------------------------
// GEMM variant, f16 X input (layer-1 xproj over the f16 h1 sequence), f16 out.
// ---------------------------------------------------------------------------
__global__ __launch_bounds__(256)
void xproj_gemm_f16(const f16* __restrict__ X, const float* __restrict__ W,
                    const float* __restrict__ b1, const float* __restrict__ b2,
                    f16* __restrict__ out)
{
    constexpr int K = HH, BM = 64, BN = 64, BK = 32;
    __shared__ float As[BK][BM + 4];
    __shared__ float Ws[BK][BN + 4];

    const int m0 = blockIdx.x * BM;
    const int n0 = blockIdx.y * BN;
    const int tid = (int)threadIdx.x;
    const int tm = tid & 15;
    const int tn = tid >> 4;
    const int ar = tid >> 2;        // 0..63  A-loader row
    const int ac = tid & 3;         // 0..3   A-loader col-group (x8 f16)
    const int lr = tid >> 3;        // 0..31  W-loader row
    const int lc = tid & 7;         // 0..7   W-loader k-group (x4)

    float acc[4][4];
    #pragma unroll
    for (int i = 0; i < 4; ++i)
        #pragma unroll
        for (int jj = 0; jj < 4; ++jj) acc[i][jj] = 0.f;

    for (int k0 = 0; k0 < K; k0 += BK) {
        f16x8 a8 = *(const f16x8*)&X[(size_t)(m0 + ar) * K + k0 + ac * 8];
        float4 w0 = *(const float4*)&W[(size_t)(n0 + lr) * K + k0 + lc * 4];
        float4 w1 = *(const float4*)&W[(size_t)(n0 + lr + 32) * K + k0 + lc * 4];
        #pragma unroll
        for (int e = 0; e < 8; ++e) As[ac * 8 + e][ar] = (float)a8[e];
        Ws[lc*4+0][lr]    = w0.x; Ws[lc*4+1][lr]    = w0.y; Ws[lc*4+2][lr]    = w0.z; Ws[lc*4+3][lr]    = w0.w;
        Ws[lc*4+0][lr+32] = w1.x; Ws[lc*4+1][lr+32] = w1.y; Ws[lc*4+2][lr+32] = w1.z; Ws[lc*4+3][lr+32] = w1.w;
        __syncthreads();
        #pragma unroll
        for (int k = 0; k < BK; ++k) {
            float4 av = *(const float4*)&As[k][tm * 4];
            float4 wv = *(const float4*)&Ws[k][tn * 4];
            acc[0][0] = fmaf(av.x, wv.x, acc[0][0]);
            acc[0][1] = fmaf(av.x, wv.y, acc[0][1]);
            acc[0][2] = fmaf(av.x, wv.z, acc[0][2]);
            acc[0][3] = fmaf(av.x, wv.w, acc[0][3]);
            acc[1][0] = fmaf(av.y, wv.x, acc[1][0]);
            acc[1][1] = fmaf(av.y, wv.y, acc[1][1]);
            acc[1][2] = fmaf(av.y, wv.z, acc[1][2]);
            acc[1][3] = fmaf(av.y, wv.w, acc[1][3]);
            acc[2][0] = fmaf(av.z, wv.x, acc[2][0]);
            acc[2][1] = fmaf(av.z, wv.y, acc[2][1]);
            acc[2][2] = fmaf(av.z, wv.z, acc[2][2]);
            acc[2][3] = fmaf(av.z, wv.w, acc[2][3]);
            acc[3][0] = fmaf(av.w, wv.x, acc[3][0]);
            acc[3][1] = fmaf(av.w, wv.y, acc[3][1]);
            acc[3][2] = fmaf(av.w, wv.z, acc[3][2]);
            acc[3][3] = fmaf(av.w, wv.w, acc[3][3]);
        }
        __syncthreads();
    }

    float4 bv1 = *(const float4*)&b1[n0 + tn * 4];
    float4 bv2 = *(const float4*)&b2[n0 + tn * 4];
    float bs0 = bv1.x + bv2.x, bs1 = bv1.y + bv2.y, bs2 = bv1.z + bv2.z, bs3 = bv1.w + bv2.w;
    #pragma unroll
    for (int i = 0; i < 4; ++i) {
        f16x4 o;
        o[0] = (f16)(acc[i][0] + bs0);
        o[1] = (f16)(acc[i][1] + bs1);
        o[2] = (f16)(acc[i][2] + bs2);
        o[3] = (f16)(acc[i][3] + bs3);
        *(f16x4*)&out[(size_t)(m0 + tm * 4 + i) * HH + n0 + tn * 4] = o;
    }
}

// ---------------------------------------------------------------------------
// MFMA Elman scan, 8 waves, 4 blocks (16 batches each).
// R5 changes vs R4 (which measured 2890 cyc/step, latency-chain-bound):
//  - xp is f16, prefetched in 4-step register chunks: the vmcnt(0) drain at
//    each __syncthreads now covers loads issued ~1 step earlier (exposure
//    ~1/4 of the previous per-step L2-miss latency).
//  - two accumulator chains (K split 0-127 / 128-255): MFMA dep chain 8 -> 4.
//  - loop-invariant lane pointer (no per-step 64-bit address mul).
// ---------------------------------------------------------------------------
__global__ __launch_bounds__(512, 2)
void rnn_scan_mfma(const f16* __restrict__ xproj,    // [B,S,H] f16 (x-proj + biases)
                   const float* __restrict__ Whh,    // [H,H] fp32
                   f16* __restrict__ hout,           // [B,S,H] f16 or nullptr
                   const float* __restrict__ Wd,     // [C,H] or nullptr
                   const float* __restrict__ bd,     // [C] or nullptr
                   float* __restrict__ outfinal,     // [B,C] or nullptr
                   int storeH)
{
    __shared__ __align__(16) f16 hbuf[2][16][HH];   // 16 KiB
    const int bg  = blockIdx.x;
    const int tid = (int)threadIdx.x;
    const int w   = tid >> 6;            // wave 0..7
    const int l   = tid & 63;
    const int l15 = l & 15;              // batch-within-group
    const int lq  = l >> 4;              // 0..3
    const int swz = (l15 & 7) << 4;

    // Whh -> f16 A-fragments: wave w rows [32w, 32w+32), mt in {0,1}
    f16x8 a[2][8];
    #pragma unroll
    for (int mt = 0; mt < 2; ++mt) {
        const int jrow = 32 * w + 16 * mt + l15;
        #pragma unroll
        for (int kt = 0; kt < 8; ++kt) {
            const float* src = Whh + (size_t)jrow * HH + 32 * kt + 8 * lq;
            float4 lo = *(const float4*)src;
            float4 hi = *(const float4*)(src + 4);
            f16x8 v;
            v[0] = (f16)lo.x; v[1] = (f16)lo.y; v[2] = (f16)lo.z; v[3] = (f16)lo.w;
            v[4] = (f16)hi.x; v[5] = (f16)hi.y; v[6] = (f16)hi.z; v[7] = (f16)hi.w;
            a[mt][kt] = v;
        }
    }

    for (int i = tid; i < 2048; i += 512) ((uint32_t*)hbuf)[i] = 0u;  // zero hbuf[0]
    __syncthreads();

    const int j0base = 32 * w + 4 * lq;              // + 16*mt per tile
    // loop-invariant per-lane xp pointer: + t*HH walks time
    const f16* xpl = xproj + ((size_t)(bg * 16 + l15) * SS) * HH + j0base;
    f16* hol = storeH ? (hout + ((size_t)(bg * 16 + l15) * SS) * HH + j0base) : nullptr;

    // chunk prefetch: 4 steps of xp live in regs
    f16x4 xq[4][2], xn[4][2];
    #pragma unroll
    for (int s = 0; s < 4; ++s)
        #pragma unroll
        for (int mt = 0; mt < 2; ++mt)
            xq[s][mt] = *(const f16x4*)(xpl + (size_t)s * HH + 16 * mt);

    int cur = 0;
    for (int t0 = 0; t0 < SS; t0 += 4) {
        // issue next chunk's 8 loads first; they drain at the s=0 barrier
        // (covered by ~1 step of work) instead of stalling every step
        const int tnb = (t0 + 4 < SS) ? (t0 + 4) : (SS - 4);
        #pragma unroll
        for (int s = 0; s < 4; ++s)
            #pragma unroll
            for (int mt = 0; mt < 2; ++mt)
                xn[s][mt] = *(const f16x4*)(xpl + (size_t)(tnb + s) * HH + 16 * mt);

        #pragma unroll
        for (int s = 0; s < 4; ++s) {
            const int t = t0 + s;
            f16x8 bfr[8];
            const char* hrow = (const char*)&hbuf[cur][l15][0];
            #pragma unroll
            for (int kt = 0; kt < 8; ++kt) {
                const int kb = (64 * kt + 16 * lq) ^ swz;
                bfr[kt] = *(const f16x8*)(hrow + kb);
            }

            // two accumulator chains per mt: K 0..127 and 128..255
            f32x4 acc0[2], acc1[2];
            #pragma unroll
            for (int mt = 0; mt < 2; ++mt) {
                acc0[mt][0] = (float)xq[s][mt][0];
                acc0[mt][1] = (float)xq[s][mt][1];
                acc0[mt][2] = (float)xq[s][mt][2];
                acc0[mt][3] = (float)xq[s][mt][3];
                acc1[mt][0] = 0.f; acc1[mt][1] = 0.f;
                acc1[mt][2] = 0.f; acc1[mt][3] = 0.f;
            }
            #pragma unroll
            for (int kt = 0; kt < 4; ++kt)
                #pragma unroll
                for (int mt = 0; mt < 2; ++mt) {
                    acc0[mt] = __builtin_amdgcn_mfma_f32_16x16x32_f16(a[mt][kt],     bfr[kt],     acc0[mt], 0, 0, 0);
                    acc1[mt] = __builtin_amdgcn_mfma_f32_16x16x32_f16(a[mt][kt + 4], bfr[kt + 4], acc1[mt], 0, 0, 0);
                }

            #pragma unroll
            for (int mt = 0; mt < 2; ++mt) {
                f16x4 h4;
                #pragma unroll
                for (int r = 0; r < 4; ++r) {
                    float z = acc0[mt][r] + acc1[mt][r];
                    float e = __expf(2.0f * z);
                    float ht = 1.0f - 2.0f * __builtin_amdgcn_rcpf(e + 1.0f);
                    h4[r] = (f16)ht;
                }
                const int jb = (64 * w + 32 * mt + 8 * lq) ^ swz;     // byte col = 2*j0
                *(f16x4*)((char*)&hbuf[cur ^ 1][l15][0] + jb) = h4;
                if (hol)
                    *(f16x4*)(hol + (size_t)t * HH + 16 * mt) = h4;
            }
            __syncthreads();
            cur ^= 1;
        }
        #pragma unroll
        for (int s = 0; s < 4; ++s)
            #pragma unroll
            for (int mt = 0; mt < 2; ++mt)
                xq[s][mt] = xn[s][mt];
    }

    // final head: out[b,c] = dot(h_last, Wd[c,:]) + bd[c]
    if (outfinal != nullptr && tid < 16 * CC) {
        const int b = tid / CC, c = tid - CC * b;
        const int sw = (b & 7) << 4;
        const char* hrow = (const char*)&hbuf[cur][b][0];
        float accv = bd[c];
        for (int k = 0; k < HH; ++k) {
            f16 hv = *(const f16*)(hrow + ((2 * k) ^ sw));
            accv += (float)hv * Wd[(size_t)c * HH + k];
        }
        outfinal[(size_t)(bg * 16 + b) * CC + c] = accv;
    }
}

// ---------------------------------------------------------------------------
extern "C" void kernel_launch(void* const* d_in, const int* in_sizes, int n_in,
                              void* d_out, int out_size, void* d_ws, size_t ws_size,
                              hipStream_t stream)
{
    const float* x    = (const float*)d_in[0];
    const float* Wih0 = (const float*)d_in[1];
    const float* Whh0 = (const float*)d_in[2];
    const float* bih0 = (const float*)d_in[3];
    const float* bhh0 = (const float*)d_in[4];
    const float* Wih1 = (const float*)d_in[5];
    const float* Whh1 = (const float*)d_in[6];
    const float* bih1 = (const float*)d_in[7];
    const float* bhh1 = (const float*)d_in[8];
    const float* Wd   = (const float*)d_in[9];
    const float* bd   = (const float*)d_in[10];
    float* out = (float*)d_out;

    f16* xp = (f16*)d_ws;                              // [B*S*H] f16 = 67 MB
    f16* h1 = xp + (size_t)BB * SS * HH;               // [B*S*H] f16 = 67 MB

    dim3 gemm_grid(BB * SS / 64, HH / 64);             // (2048, 4)

    // Layer 0
    xproj_gemm<FF><<<gemm_grid, 256, 0, stream>>>(x, Wih0, bih0, bhh0, xp);
    rnn_scan_mfma<<<4, 512, 0, stream>>>(xp, Whh0, h1, nullptr, nullptr, nullptr, 1);

    // Layer 1 + head
    xproj_gemm_f16<<<gemm_grid, 256, 0, stream>>>(h1, Wih1, bih1, bhh1, xp);
    rnn_scan_mfma<<<4, 512, 0, stream>>>(xp, Whh1, nullptr, Wd, bd, out, 0);
}

// Round 8
// 3552.428 us; speedup vs baseline: 1.4078x; 1.1352x over previous
//
#include <hip/hip_runtime.h>
#include <cstdint>
#include <cstddef>

#define BB 64
#define SS 2048
#define FF 128
#define HH 256
#define CC 10
#define HP (HH + 8)   // padded h row: 264 f16 = 528B; 528 mod 128 = 16 -> bank
                      // window rotates 16B/row -> conflict-free b128 reads

typedef _Float16 f16;
typedef _Float16 f16x8 __attribute__((ext_vector_type(8)));
typedef _Float16 f16x4 __attribute__((ext_vector_type(4)));
typedef float f32x4 __attribute__((ext_vector_type(4)));

// ---------------------------------------------------------------------------
// GEMM (f32 X): xp[m,n] = sum_k X[m,k]*W[n,k] + b1[n] + b2[n], stored f16.
// ---------------------------------------------------------------------------
template<int K>
__global__ __launch_bounds__(256)
void xproj_gemm(const float* __restrict__ X, const float* __restrict__ W,
                const float* __restrict__ b1, const float* __restrict__ b2,
                f16* __restrict__ out)
{
    constexpr int BM = 64, BN = 64, BK = 32;
    __shared__ float As[BK][BM + 4];
    __shared__ float Ws[BK][BN + 4];

    const int m0 = blockIdx.x * BM;
    const int n0 = blockIdx.y * BN;
    const int tid = (int)threadIdx.x;
    const int tm = tid & 15;
    const int tn = tid >> 4;
    const int lr = tid >> 3;
    const int lc = tid & 7;

    float acc[4][4];
    #pragma unroll
    for (int i = 0; i < 4; ++i)
        #pragma unroll
        for (int jj = 0; jj < 4; ++jj) acc[i][jj] = 0.f;

    for (int k0 = 0; k0 < K; k0 += BK) {
        float4 a0 = *(const float4*)&X[(size_t)(m0 + lr) * K + k0 + lc * 4];
        float4 a1 = *(const float4*)&X[(size_t)(m0 + lr + 32) * K + k0 + lc * 4];
        float4 w0 = *(const float4*)&W[(size_t)(n0 + lr) * K + k0 + lc * 4];
        float4 w1 = *(const float4*)&W[(size_t)(n0 + lr + 32) * K + k0 + lc * 4];
        As[lc*4+0][lr]    = a0.x; As[lc*4+1][lr]    = a0.y; As[lc*4+2][lr]    = a0.z; As[lc*4+3][lr]    = a0.w;
        As[lc*4+0][lr+32] = a1.x; As[lc*4+1][lr+32] = a1.y; As[lc*4+2][lr+32] = a1.z; As[lc*4+3][lr+32] = a1.w;
        Ws[lc*4+0][lr]    = w0.x; Ws[lc*4+1][lr]    = w0.y; Ws[lc*4+2][lr]    = w0.z; Ws[lc*4+3][lr]    = w0.w;
        Ws[lc*4+0][lr+32] = w1.x; Ws[lc*4+1][lr+32] = w1.y; Ws[lc*4+2][lr+32] = w1.z; Ws[lc*4+3][lr+32] = w1.w;
        __syncthreads();
        #pragma unroll
        for (int k = 0; k < BK; ++k) {
            float4 av = *(const float4*)&As[k][tm * 4];
            float4 wv = *(const float4*)&Ws[k][tn * 4];
            acc[0][0] = fmaf(av.x, wv.x, acc[0][0]);
            acc[0][1] = fmaf(av.x, wv.y, acc[0][1]);
            acc[0][2] = fmaf(av.x, wv.z, acc[0][2]);
            acc[0][3] = fmaf(av.x, wv.w, acc[0][3]);
            acc[1][0] = fmaf(av.y, wv.x, acc[1][0]);
            acc[1][1] = fmaf(av.y, wv.y, acc[1][1]);
            acc[1][2] = fmaf(av.y, wv.z, acc[1][2]);
            acc[1][3] = fmaf(av.y, wv.w, acc[1][3]);
            acc[2][0] = fmaf(av.z, wv.x, acc[2][0]);
            acc[2][1] = fmaf(av.z, wv.y, acc[2][1]);
            acc[2][2] = fmaf(av.z, wv.z, acc[2][2]);
            acc[2][3] = fmaf(av.z, wv.w, acc[2][3]);
            acc[3][0] = fmaf(av.w, wv.x, acc[3][0]);
            acc[3][1] = fmaf(av.w, wv.y, acc[3][1]);
            acc[3][2] = fmaf(av.w, wv.z, acc[3][2]);
            acc[3][3] = fmaf(av.w, wv.w, acc[3][3]);
        }
        __syncthreads();
    }

    float4 bv1 = *(const float4*)&b1[n0 + tn * 4];
    float4 bv2 = *(const float4*)&b2[n0 + tn * 4];
    float bs0 = bv1.x + bv2.x, bs1 = bv1.y + bv2.y, bs2 = bv1.z + bv2.z, bs3 = bv1.w + bv2.w;
    #pragma unroll
    for (int i = 0; i < 4; ++i) {
        f16x4 o;
        o[0] = (f16)(acc[i][0] + bs0);
        o[1] = (f16)(acc[i][1] + bs1);
        o[2] = (f16)(acc[i][2] + bs2);
        o[3] = (f16)(acc[i][3] + bs3);
        *(f16x4*)&out[(size_t)(m0 + tm * 4 + i) * HH + n0 + tn * 4] = o;
    }
}

// ---------------------------------------------------------------------------
// GEMM variant, f16 X input (layer-1 xproj over the f16 h1 sequence), f16 out.
// ---------------------------------------------------------------------------
__global__ __launch_bounds__(256)
void xproj_gemm_f16(const f16* __restrict__ X, const float* __restrict__ W,
                    const float* __restrict__ b1, const float* __restrict__ b2,
                    f16* __restrict__ out)
{
    constexpr int K = HH, BM = 64, BN = 64, BK = 32;
    __shared__ float As[BK][BM + 4];
    __shared__ float Ws[BK][BN + 4];

    const int m0 = blockIdx.x * BM;
    const int n0 = blockIdx.y * BN;
    const int tid = (int)threadIdx.x;
    const int tm = tid & 15;
    const int tn = tid >> 4;
    const int ar = tid >> 2;
    const int ac = tid & 3;
    const int lr = tid >> 3;
    const int lc = tid & 7;

    float acc[4][4];
    #pragma unroll
    for (int i = 0; i < 4; ++i)
        #pragma unroll
        for (int jj = 0; jj < 4; ++jj) acc[i][jj] = 0.f;

    for (int k0 = 0; k0 < K; k0 += BK) {
        f16x8 a8 = *(const f16x8*)&X[(size_t)(m0 + ar) * K + k0 + ac * 8];
        float4 w0 = *(const float4*)&W[(size_t)(n0 + lr) * K + k0 + lc * 4];
        float4 w1 = *(const float4*)&W[(size_t)(n0 + lr + 32) * K + k0 + lc * 4];
        #pragma unroll
        for (int e = 0; e < 8; ++e) As[ac * 8 + e][ar] = (float)a8[e];
        Ws[lc*4+0][lr]    = w0.x; Ws[lc*4+1][lr]    = w0.y; Ws[lc*4+2][lr]    = w0.z; Ws[lc*4+3][lr]    = w0.w;
        Ws[lc*4+0][lr+32] = w1.x; Ws[lc*4+1][lr+32] = w1.y; Ws[lc*4+2][lr+32] = w1.z; Ws[lc*4+3][lr+32] = w1.w;
        __syncthreads();
        #pragma unroll
        for (int k = 0; k < BK; ++k) {
            float4 av = *(const float4*)&As[k][tm * 4];
            float4 wv = *(const float4*)&Ws[k][tn * 4];
            acc[0][0] = fmaf(av.x, wv.x, acc[0][0]);
            acc[0][1] = fmaf(av.x, wv.y, acc[0][1]);
            acc[0][2] = fmaf(av.x, wv.z, acc[0][2]);
            acc[0][3] = fmaf(av.x, wv.w, acc[0][3]);
            acc[1][0] = fmaf(av.y, wv.x, acc[1][0]);
            acc[1][1] = fmaf(av.y, wv.y, acc[1][1]);
            acc[1][2] = fmaf(av.y, wv.z, acc[1][2]);
            acc[1][3] = fmaf(av.y, wv.w, acc[1][3]);
            acc[2][0] = fmaf(av.z, wv.x, acc[2][0]);
            acc[2][1] = fmaf(av.z, wv.y, acc[2][1]);
            acc[2][2] = fmaf(av.z, wv.z, acc[2][2]);
            acc[2][3] = fmaf(av.z, wv.w, acc[2][3]);
            acc[3][0] = fmaf(av.w, wv.x, acc[3][0]);
            acc[3][1] = fmaf(av.w, wv.y, acc[3][1]);
            acc[3][2] = fmaf(av.w, wv.z, acc[3][2]);
            acc[3][3] = fmaf(av.w, wv.w, acc[3][3]);
        }
        __syncthreads();
    }

    float4 bv1 = *(const float4*)&b1[n0 + tn * 4];
    float4 bv2 = *(const float4*)&b2[n0 + tn * 4];
    float bs0 = bv1.x + bv2.x, bs1 = bv1.y + bv2.y, bs2 = bv1.z + bv2.z, bs3 = bv1.w + bv2.w;
    #pragma unroll
    for (int i = 0; i < 4; ++i) {
        f16x4 o;
        o[0] = (f16)(acc[i][0] + bs0);
        o[1] = (f16)(acc[i][1] + bs1);
        o[2] = (f16)(acc[i][2] + bs2);
        o[3] = (f16)(acc[i][3] + bs3);
        *(f16x4*)&out[(size_t)(m0 + tm * 4 + i) * HH + n0 + tn * 4] = o;
    }
}

// ---------------------------------------------------------------------------
// MFMA Elman scan, 8 waves, 8 blocks x 8 batches.
// R6 changes vs R5 (2330 cyc/step, 1280 of which were LDS bank conflicts):
//  - LDS banking FIXED: dropped the (broken) XOR swizzle; h rows padded to
//    264 f16 (528B). 528 mod 128 = 16 -> each row's bank window rotates by
//    16B; b128 reads land exactly 32B/bank/transaction = conflict-free.
//  - 8 batches/block, 8 blocks: lanes l15>=8 mirror lanes l15&7 (same LDS /
//    xp addresses -> same-address broadcast = free). Halves effective LDS
//    volume per CU, doubles active CUs.
//  - tanh epilogue predicated to l15<8 (trans ops are per-lane rate).
// ---------------------------------------------------------------------------
__global__ __launch_bounds__(512, 2)
void rnn_scan_mfma(const f16* __restrict__ xproj,    // [B,S,H] f16 (x-proj + biases)
                   const float* __restrict__ Whh,    // [H,H] fp32
                   f16* __restrict__ hout,           // [B,S,H] f16 or nullptr
                   const float* __restrict__ Wd,     // [C,H] or nullptr
                   const float* __restrict__ bd,     // [C] or nullptr
                   float* __restrict__ outfinal,     // [B,C] or nullptr
                   int storeH)
{
    __shared__ __align__(16) f16 hbuf[2][8][HP];    // 2 x 8 rows x 264 f16
    const int bg  = blockIdx.x;          // batches [8bg, 8bg+8)
    const int tid = (int)threadIdx.x;
    const int w   = tid >> 6;            // wave 0..7
    const int l   = tid & 63;
    const int l15 = l & 15;              // MFMA col; batch = l15 & 7 (mirrored)
    const int b8  = l15 & 7;
    const int lq  = l >> 4;              // 0..3

    // Whh -> f16 A-fragments: wave w rows [32w, 32w+32), mt in {0,1}
    f16x8 a[2][8];
    #pragma unroll
    for (int mt = 0; mt < 2; ++mt) {
        const int jrow = 32 * w + 16 * mt + l15;
        #pragma unroll
        for (int kt = 0; kt < 8; ++kt) {
            const float* src = Whh + (size_t)jrow * HH + 32 * kt + 8 * lq;
            float4 lo = *(const float4*)src;
            float4 hi = *(const float4*)(src + 4);
            f16x8 v;
            v[0] = (f16)lo.x; v[1] = (f16)lo.y; v[2] = (f16)lo.z; v[3] = (f16)lo.w;
            v[4] = (f16)hi.x; v[5] = (f16)hi.y; v[6] = (f16)hi.z; v[7] = (f16)hi.w;
            a[mt][kt] = v;
        }
    }

    for (int i = tid; i < 2 * 8 * HP / 2; i += 512) ((uint32_t*)hbuf)[i] = 0u;
    __syncthreads();

    const int j0base = 32 * w + 4 * lq;              // + 16*mt per tile
    const f16* xpl = xproj + ((size_t)(bg * 8 + b8) * SS) * HH + j0base;
    f16* hol = storeH ? (hout + ((size_t)(bg * 8 + b8) * SS) * HH + j0base) : nullptr;

    // chunk prefetch: 4 steps of xp live in regs
    f16x4 xq[4][2], xn[4][2];
    #pragma unroll
    for (int s = 0; s < 4; ++s)
        #pragma unroll
        for (int mt = 0; mt < 2; ++mt)
            xq[s][mt] = *(const f16x4*)(xpl + (size_t)s * HH + 16 * mt);

    int cur = 0;
    for (int t0 = 0; t0 < SS; t0 += 4) {
        const int tnb = (t0 + 4 < SS) ? (t0 + 4) : (SS - 4);
        #pragma unroll
        for (int s = 0; s < 4; ++s)
            #pragma unroll
            for (int mt = 0; mt < 2; ++mt)
                xn[s][mt] = *(const f16x4*)(xpl + (size_t)(tnb + s) * HH + 16 * mt);

        #pragma unroll
        for (int s = 0; s < 4; ++s) {
            const int t = t0 + s;
            // B fragments: row = batch (mirrored for l15>=8 -> broadcast)
            f16x8 bfr[8];
            const f16* hrow = &hbuf[cur][b8][0];
            #pragma unroll
            for (int kt = 0; kt < 8; ++kt)
                bfr[kt] = *(const f16x8*)(hrow + 32 * kt + 8 * lq);

            // two accumulator chains per mt: K 0..127 and 128..255
            f32x4 acc0[2], acc1[2];
            #pragma unroll
            for (int mt = 0; mt < 2; ++mt) {
                acc0[mt][0] = (float)xq[s][mt][0];
                acc0[mt][1] = (float)xq[s][mt][1];
                acc0[mt][2] = (float)xq[s][mt][2];
                acc0[mt][3] = (float)xq[s][mt][3];
                acc1[mt][0] = 0.f; acc1[mt][1] = 0.f;
                acc1[mt][2] = 0.f; acc1[mt][3] = 0.f;
            }
            #pragma unroll
            for (int kt = 0; kt < 4; ++kt)
                #pragma unroll
                for (int mt = 0; mt < 2; ++mt) {
                    acc0[mt] = __builtin_amdgcn_mfma_f32_16x16x32_f16(a[mt][kt],     bfr[kt],     acc0[mt], 0, 0, 0);
                    acc1[mt] = __builtin_amdgcn_mfma_f32_16x16x32_f16(a[mt][kt + 4], bfr[kt + 4], acc1[mt], 0, 0, 0);
                }

            if (l15 < 8) {   // real batches only: halves trans-pipe work
                #pragma unroll
                for (int mt = 0; mt < 2; ++mt) {
                    f16x4 h4;
                    #pragma unroll
                    for (int r = 0; r < 4; ++r) {
                        float z = acc0[mt][r] + acc1[mt][r];
                        float e = __expf(2.0f * z);
                        float ht = 1.0f - 2.0f * __builtin_amdgcn_rcpf(e + 1.0f);
                        h4[r] = (f16)ht;
                    }
                    // j0 = 32w + 16mt + 4lq
                    *(f16x4*)(&hbuf[cur ^ 1][b8][0] + j0base + 16 * mt) = h4;
                    if (hol)
                        *(f16x4*)(hol + (size_t)t * HH + 16 * mt) = h4;
                }
            }
            __syncthreads();
            cur ^= 1;
        }
        #pragma unroll
        for (int s = 0; s < 4; ++s)
            #pragma unroll
            for (int mt = 0; mt < 2; ++mt)
                xq[s][mt] = xn[s][mt];
    }

    // final head: out[b,c] = dot(h_last, Wd[c,:]) + bd[c]
    if (outfinal != nullptr && tid < 8 * CC) {
        const int b = tid / CC, c = tid - CC * b;
        const f16* hrow = &hbuf[cur][b][0];
        float accv = bd[c];
        for (int k = 0; k < HH; ++k)
            accv += (float)hrow[k] * Wd[(size_t)c * HH + k];
        outfinal[(size_t)(bg * 8 + b) * CC + c] = accv;
    }
}

// ---------------------------------------------------------------------------
extern "C" void kernel_launch(void* const* d_in, const int* in_sizes, int n_in,
                              void* d_out, int out_size, void* d_ws, size_t ws_size,
                              hipStream_t stream)
{
    const float* x    = (const float*)d_in[0];
    const float* Wih0 = (const float*)d_in[1];
    const float* Whh0 = (const float*)d_in[2];
    const float* bih0 = (const float*)d_in[3];
    const float* bhh0 = (const float*)d_in[4];
    const float* Wih1 = (const float*)d_in[5];
    const float* Whh1 = (const float*)d_in[6];
    const float* bih1 = (const float*)d_in[7];
    const float* bhh1 = (const float*)d_in[8];
    const float* Wd   = (const float*)d_in[9];
    const float* bd   = (const float*)d_in[10];
    float* out = (float*)d_out;

    f16* xp = (f16*)d_ws;                              // [B*S*H] f16 = 67 MB
    f16* h1 = xp + (size_t)BB * SS * HH;               // [B*S*H] f16 = 67 MB

    dim3 gemm_grid(BB * SS / 64, HH / 64);             // (2048, 4)

    // Layer 0
    xproj_gemm<FF><<<gemm_grid, 256, 0, stream>>>(x, Wih0, bih0, bhh0, xp);
    rnn_scan_mfma<<<8, 512, 0, stream>>>(xp, Whh0, h1, nullptr, nullptr, nullptr, 1);

    // Layer 1 + head
    xproj_gemm_f16<<<gemm_grid, 256, 0, stream>>>(h1, Wih1, bih1, bhh1, xp);
    rnn_scan_mfma<<<8, 512, 0, stream>>>(xp, Whh1, nullptr, Wd, bd, out, 0);
}